// Round 5
// baseline (1033.406 us; speedup 1.0000x reference)
//
#include <hip/hip_runtime.h>
#include <cstdint>
#include <cstddef>

#define B_SZ   4
#define N_PTS  2048
#define KNN    20
#define BN_ROWS (B_SZ * N_PTS)
#define EPSV   1e-5f
#define SLOPEV 0.2f

#define MODE_GD   0
#define MODE_DIST 1
#define MODE_ACC  2

// ---------------------------------------------------------------- transpose + xx
// x (B,3,N) -> xt (B*N, 3); xx[i] = |x_i|^2
__global__ void k_transpose(const float* __restrict__ x, float* __restrict__ xt,
                            float* __restrict__ xx)
{
    int i = blockIdx.x * 256 + threadIdx.x;
    if (i >= BN_ROWS) return;
    int b = i >> 11, n = i & 2047;
    float v0 = x[((b * 3 + 0) << 11) + n];
    float v1 = x[((b * 3 + 1) << 11) + n];
    float v2 = x[((b * 3 + 2) << 11) + n];
    xt[i * 3 + 0] = v0; xt[i * 3 + 1] = v1; xt[i * 3 + 2] = v2;
    xx[i] = fmaf(v0, v0, fmaf(v1, v1, v2 * v2));
}

// ---------------------------------------------------------------- batched weight prep
// For each layer: W (O,2C) -> [W1 rows (O,C) | (W2-W1) rows (O,C)] at fixed offsets.
__global__ void k_prepw_all(const float* __restrict__ W1, const float* __restrict__ W2,
                            const float* __restrict__ W3, const float* __restrict__ W4,
                            float* __restrict__ wc)
{
    int i = blockIdx.x * 256 + threadIdx.x;
    const float* W; int O, C, off;
    if      (i < 384)   { W = W1; O = 64;  C = 3;   off = 0; }
    else if (i < 8576)  { W = W2; O = 64;  C = 64;  off = 384; }
    else if (i < 24960) { W = W3; O = 128; C = 64;  off = 8576; }
    else if (i < 90496) { W = W4; O = 256; C = 128; off = 24960; }
    else return;
    int e = i - off, j = e / C, c = e - j * C;
    float v;
    if (j < O) v = W[j * 2 * C + c];
    else { int jo = j - O; v = W[jo * 2 * C + C + c] - W[jo * 2 * C + c]; }
    wc[i] = v;
}

// ---------------------------------------------------------------- 128x128 GEMM core
// MODE_GD  : C = A(MxK) @ Bm(NnxK)^T, cols < Nn/2 -> C1 (gtab), rest -> C2 (dtab)
// MODE_DIST: per batch z: D2 = 2*A A^T - xx_i - xx_j, diagonal forced to 0
// MODE_ACC : split-K halves over blockIdx.z, atomicAdd into zero-initialized C1
#define MM_BODY(kk) do {                                                          \
    float4 a0 = *(const float4*)&As[(kk) * LDT + ty * 4];                         \
    float4 a1 = *(const float4*)&As[(kk) * LDT + 64 + ty * 4];                    \
    float4 c0 = *(const float4*)&Bs[(kk) * LDT + tx * 4];                         \
    float4 c1 = *(const float4*)&Bs[(kk) * LDT + 64 + tx * 4];                    \
    float av[2][4] = {{a0.x,a0.y,a0.z,a0.w},{a1.x,a1.y,a1.z,a1.w}};               \
    float bw[2][4] = {{c0.x,c0.y,c0.z,c0.w},{c1.x,c1.y,c1.z,c1.w}};               \
    _Pragma("unroll") for (int ih = 0; ih < 2; ++ih)                              \
    _Pragma("unroll") for (int jh = 0; jh < 2; ++jh)                              \
    _Pragma("unroll") for (int ii = 0; ii < 4; ++ii)                              \
    _Pragma("unroll") for (int jj = 0; jj < 4; ++jj)                              \
        acc[ih][jh][ii][jj] = fmaf(av[ih][ii], bw[jh][jj], acc[ih][jh][ii][jj]);  \
} while (0)

template<int MODE, bool VEC>
__launch_bounds__(256)
__global__ void k_mm128(const float* __restrict__ A, int lda,
                        const float* __restrict__ Bm, int ldb,
                        const float* __restrict__ xx, int b0,
                        float* __restrict__ C1, float* __restrict__ C2,
                        int Nn, int Kd)
{
    constexpr int LDT = 132;
    __shared__ float As[32 * LDT];
    __shared__ float Bs[32 * LDT];
    const int tid = threadIdx.x;
    const int tx  = tid & 15;
    const int ty  = tid >> 4;
    const int m0  = blockIdx.y * 128;
    const int n0  = blockIdx.x * 128;

    const float* Ab;
    const float* Bb;
    int ldbe;
    if constexpr (MODE == MODE_DIST) {
        const int b = b0 + blockIdx.z;
        Ab = A + (size_t)b * N_PTS * lda;
        Bb = Ab;
        ldbe = lda;
    } else {
        Ab = A; Bb = Bm; ldbe = ldb;
    }

    int kbeg = 0, kstop = Kd;
    if constexpr (MODE == MODE_ACC) {
        int half = Kd >> 1;
        kbeg  = blockIdx.z * half;
        kstop = kbeg + half;
    }

    float acc[2][2][4][4] = {};

    for (int k0 = kbeg; k0 < kstop; k0 += 32) {
        #pragma unroll
        for (int r = 0; r < 4; ++r) {
            int e = r * 256 + tid, row = e >> 3, kq = e & 7;
            if constexpr (VEC) {
                float4 v = *(const float4*)&Ab[(size_t)(m0 + row) * lda + k0 + kq * 4];
                As[(kq * 4 + 0) * LDT + row] = v.x;
                As[(kq * 4 + 1) * LDT + row] = v.y;
                As[(kq * 4 + 2) * LDT + row] = v.z;
                As[(kq * 4 + 3) * LDT + row] = v.w;
            } else {
                #pragma unroll
                for (int j = 0; j < 4; ++j) {
                    int kg = k0 + kq * 4 + j;
                    As[(kq * 4 + j) * LDT + row] =
                        (kg < Kd) ? Ab[(size_t)(m0 + row) * lda + kg] : 0.f;
                }
            }
        }
        #pragma unroll
        for (int r = 0; r < 4; ++r) {
            int e = r * 256 + tid, row = e >> 3, kq = e & 7;
            if constexpr (VEC) {
                float4 v = *(const float4*)&Bb[(size_t)(n0 + row) * ldbe + k0 + kq * 4];
                Bs[(kq * 4 + 0) * LDT + row] = v.x;
                Bs[(kq * 4 + 1) * LDT + row] = v.y;
                Bs[(kq * 4 + 2) * LDT + row] = v.z;
                Bs[(kq * 4 + 3) * LDT + row] = v.w;
            } else {
                #pragma unroll
                for (int j = 0; j < 4; ++j) {
                    int kg = k0 + kq * 4 + j;
                    Bs[(kq * 4 + j) * LDT + row] =
                        (kg < Kd) ? Bb[(size_t)(n0 + row) * ldbe + kg] : 0.f;
                }
            }
        }
        __syncthreads();

        int klen = kstop - k0; if (klen > 32) klen = 32;
        if (klen == 32) {
            #pragma unroll 8
            for (int kk = 0; kk < 32; ++kk) MM_BODY(kk);
        } else {
            for (int kk = 0; kk < klen; ++kk) MM_BODY(kk);
        }
        __syncthreads();
    }

    if constexpr (MODE == MODE_DIST) {
        const int b = b0 + blockIdx.z;
        const float* xxb = xx + b * N_PTS;
        float xj[2][4];
        #pragma unroll
        for (int jh = 0; jh < 2; ++jh) {
            float4 v = *(const float4*)&xxb[n0 + jh * 64 + tx * 4];
            xj[jh][0] = v.x; xj[jh][1] = v.y; xj[jh][2] = v.z; xj[jh][3] = v.w;
        }
        #pragma unroll
        for (int ih = 0; ih < 2; ++ih)
            #pragma unroll
            for (int i = 0; i < 4; ++i) {
                int gi = m0 + ih * 64 + ty * 4 + i;
                float xi = xxb[gi];
                size_t base = ((size_t)blockIdx.z * N_PTS + gi) * N_PTS;
                #pragma unroll
                for (int jh = 0; jh < 2; ++jh) {
                    int gj = n0 + jh * 64 + tx * 4;
                    float4 v;
                    v.x = 2.f * acc[ih][jh][i][0] - xi - xj[jh][0];
                    v.y = 2.f * acc[ih][jh][i][1] - xi - xj[jh][1];
                    v.z = 2.f * acc[ih][jh][i][2] - xi - xj[jh][2];
                    v.w = 2.f * acc[ih][jh][i][3] - xi - xj[jh][3];
                    if (gi == gj + 0) v.x = 0.f;   // self-distance exact 0
                    if (gi == gj + 1) v.y = 0.f;
                    if (gi == gj + 2) v.z = 0.f;
                    if (gi == gj + 3) v.w = 0.f;
                    *(float4*)&C1[base + gj] = v;
                }
            }
    } else if constexpr (MODE == MODE_GD) {
        const int Oo = Nn >> 1;
        #pragma unroll
        for (int ih = 0; ih < 2; ++ih)
            #pragma unroll
            for (int i = 0; i < 4; ++i) {
                int row = m0 + ih * 64 + ty * 4 + i;
                #pragma unroll
                for (int jh = 0; jh < 2; ++jh) {
                    int colg = n0 + jh * 64 + tx * 4;
                    float4 v = make_float4(acc[ih][jh][i][0], acc[ih][jh][i][1],
                                           acc[ih][jh][i][2], acc[ih][jh][i][3]);
                    if (colg < Oo) *(float4*)&C1[(size_t)row * Oo + colg] = v;
                    else           *(float4*)&C2[(size_t)row * Oo + colg - Oo] = v;
                }
            }
    } else {  // MODE_ACC
        #pragma unroll
        for (int ih = 0; ih < 2; ++ih)
            #pragma unroll
            for (int i = 0; i < 4; ++i) {
                int row = m0 + ih * 64 + ty * 4 + i;
                #pragma unroll
                for (int jh = 0; jh < 2; ++jh) {
                    int colg = n0 + jh * 64 + tx * 4;
                    float* p = &C1[(size_t)row * Nn + colg];
                    atomicAdd(p + 0, acc[ih][jh][i][0]);
                    atomicAdd(p + 1, acc[ih][jh][i][1]);
                    atomicAdd(p + 2, acc[ih][jh][i][2]);
                    atomicAdd(p + 3, acc[ih][jh][i][3]);
                }
            }
    }
}

// ---------------------------------------------------------------- top-20 select
__launch_bounds__(256)
__global__ void k_select(const float* __restrict__ D2, int b0, int* __restrict__ idx_out)
{
    const int lane = threadIdx.x & 63;
    const int w    = threadIdx.x >> 6;
    const int qloc = blockIdx.x * 4 + w;
    const int bl   = qloc >> 11;
    const int n    = qloc & 2047;
    const float* row = D2 + (size_t)qloc * N_PTS;

    unsigned key[32];
    #pragma unroll
    for (int c = 0; c < 8; ++c) {
        float4 v = *(const float4*)&row[c * 256 + lane * 4];
        float vv[4] = {v.x, v.y, v.z, v.w};
        #pragma unroll
        for (int r = 0; r < 4; ++r) {
            unsigned u = __float_as_uint(vv[r]);
            key[c * 4 + r] = ((int)u >= 0) ? (u | 0x80000000u) : ~u;
        }
    }

    unsigned lo = 0u, hi = 0xFFFFFFFFu;
    while (lo < hi) {
        unsigned mid = lo + ((hi - lo) >> 1);
        int cnt = 0;
        #pragma unroll
        for (int e = 0; e < 32; ++e) cnt += (key[e] > mid) ? 1 : 0;
        #pragma unroll
        for (int s = 32; s >= 1; s >>= 1) cnt += __shfl_xor(cnt, s, 64);
        cnt = __builtin_amdgcn_readfirstlane(cnt);
        if (cnt < KNN) hi = mid; else lo = mid + 1;
    }
    const unsigned T = lo;

    int* outp = idx_out + (size_t)((b0 + bl) * N_PTS + n) * KNN;
    const unsigned long long ltmask = (lane == 0) ? 0ull : (~0ull >> (64 - lane));
    int base = 0;
    #pragma unroll
    for (int e = 0; e < 32; ++e) {
        bool p = key[e] > T;
        unsigned long long m = __ballot(p);
        if (p) {
            int pos = base + __popcll(m & ltmask);
            outp[pos] = (e >> 2) * 256 + lane * 4 + (e & 3);
        }
        base += __popcll(m);
    }
    for (int e = 0; e < 32 && base < KNN; ++e) {
        bool p = key[e] == T;
        unsigned long long m = __ballot(p);
        if (p) {
            int pos = base + __popcll(m & ltmask);
            if (pos < KNN) outp[pos] = (e >> 2) * 256 + lane * 4 + (e & 3);
        }
        base += __popcll(m);
    }
}

// ---------------------------------------------------------------- gather + stats
// h[n,k,o] = gtab[idx[n,k]][o] + dtab[n][o]; emits per-(n,o) max/min over k
// and banked channel sum/sumsq.
template<int O, int NSEQ>
__launch_bounds__(256)
__global__ void k_gather(const float* __restrict__ gtab, const float* __restrict__ dtab,
                         const int* __restrict__ idx,
                         float* __restrict__ hmax, float* __restrict__ hmin,
                         float* __restrict__ ssum, float* __restrict__ ssumsq)
{
    constexpr int NPB = 256 / O;
    const int grp = threadIdx.x / O;
    const int o   = threadIdx.x & (O - 1);
    float accS = 0.f, accS2 = 0.f;
    const int rowsPerBlock = NPB * NSEQ;
    for (int s = 0; s < NSEQ; ++s) {
        int row = blockIdx.x * rowsPerBlock + s * NPB + grp;
        const int* ip = idx + (size_t)row * KNN;
        int bbase = (row >> 11) << 11;
        float gmax = -INFINITY, gmin = INFINITY, gs = 0.f, gs2 = 0.f;
        for (int k = 0; k < KNN; ++k) {
            int nb = ip[k];
            float v = gtab[(size_t)(bbase + nb) * O + o];
            gmax = fmaxf(gmax, v);
            gmin = fminf(gmin, v);
            gs  += v;
            gs2  = fmaf(v, v, gs2);
        }
        float d = dtab[(size_t)row * O + o];
        hmax[(size_t)row * O + o] = gmax + d;
        hmin[(size_t)row * O + o] = gmin + d;
        accS  += gs + (float)KNN * d;
        accS2 += gs2 + 2.f * d * gs + (float)KNN * d * d;
    }
    int bank = blockIdx.x & 63;
    atomicAdd(&ssum[bank * O + o], accS);
    atomicAdd(&ssumsq[bank * O + o], accS2);
}

// ---------------------------------------------------------------- normalize (+BN finalize, +xx)
// Each thread derives its channel's (scale, shift) from banked stats, then
// streams row-groups: y = lrelu(bn(h)) -> xc slice; optionally xx[row] = sum y^2.
template<int O, bool WRITE_XX>
__launch_bounds__(256)
__global__ void k_normalize(const float* __restrict__ hmax, const float* __restrict__ hmin,
                            const float* __restrict__ ssum, const float* __restrict__ ssumsq,
                            const float* __restrict__ gamma, const float* __restrict__ beta,
                            float invM, float* __restrict__ xcs, float* __restrict__ xx)
{
    const int tid = threadIdx.x;
    const int o   = tid & (O - 1);
    float s = 0.f, s2 = 0.f;
    #pragma unroll 8
    for (int bk = 0; bk < 64; ++bk) { s += ssum[bk * O + o]; s2 += ssumsq[bk * O + o]; }
    float mean = s * invM;
    float var  = fmaf(-mean, mean, s2 * invM);
    float sc   = gamma[o] * rsqrtf(var + EPSV);
    float sh   = beta[o] - mean * sc;

    constexpr int R = 256 / O;
    const int rloc = tid / O;
    __shared__ float part[4];
    const int ngroups = BN_ROWS / R;
    for (int gidx = blockIdx.x; gidx < ngroups; gidx += gridDim.x) {
        int row = gidx * R + rloc;
        size_t i = (size_t)row * O + o;
        float h = (sc >= 0.f) ? hmax[i] : hmin[i];
        float y = fmaf(h, sc, sh);
        y = (y >= 0.f) ? y : SLOPEV * y;
        xcs[(size_t)row * 512 + o] = y;
        if constexpr (WRITE_XX) {
            float p = y * y;
            #pragma unroll
            for (int sft = 32; sft >= 1; sft >>= 1) p += __shfl_xor(p, sft, 64);
            if constexpr (O == 64) {
                if ((tid & 63) == 0) xx[row] = p;
            } else {
                if ((tid & 63) == 0) part[tid >> 6] = p;
                __syncthreads();
                if constexpr (O == 128) {
                    if (tid < 2) xx[gidx * R + tid] = part[2 * tid] + part[2 * tid + 1];
                } else {
                    if (tid == 0) xx[gidx * R] = (part[0] + part[1]) + (part[2] + part[3]);
                }
                __syncthreads();
            }
        }
    }
}

// ---------------------------------------------------------------- layer-5 stats (16 banks)
__global__ void k_stats5(const float* __restrict__ h, float* __restrict__ ssum, float* __restrict__ ssumsq)
{
    int o  = blockIdx.y * 256 + threadIdx.x;
    int r0 = blockIdx.x * 512;
    float s = 0.f, s2 = 0.f;
    for (int r = 0; r < 512; ++r) {
        float v = h[(size_t)(r0 + r) * 1024 + o];
        s += v; s2 = fmaf(v, v, s2);
    }
    ssum[blockIdx.x * 1024 + o]   = s;
    ssumsq[blockIdx.x * 1024 + o] = s2;
}

// ---------------------------------------------------------------- normalize+lrelu + 64-seg max/sum (+finalize)
__global__ void k_seg(const float* __restrict__ h,
                      const float* __restrict__ ssum, const float* __restrict__ ssumsq,
                      const float* __restrict__ gamma, const float* __restrict__ beta,
                      float* __restrict__ smax, float* __restrict__ ssumseg)
{
    int f = blockIdx.y * 256 + threadIdx.x;
    float s = 0.f, s2 = 0.f;
    #pragma unroll
    for (int bk = 0; bk < 16; ++bk) { s += ssum[bk * 1024 + f]; s2 += ssumsq[bk * 1024 + f]; }
    const float invM = 1.f / (float)BN_ROWS;
    float mean = s * invM;
    float var  = fmaf(-mean, mean, s2 * invM);
    float sc   = gamma[f] * rsqrtf(var + EPSV);
    float sh   = beta[f] - mean * sc;

    int seg = blockIdx.x;
    float mx = -INFINITY, sm = 0.f;
    int n0 = seg * 64;
    for (int i = 0; i < 64; ++i) {
        float v = fmaf(h[(size_t)(n0 + i) * 1024 + f], sc, sh);
        v = (v >= 0.f) ? v : SLOPEV * v;
        mx = fmaxf(mx, v); sm += v;
    }
    smax[(size_t)seg * 1024 + f]    = mx;
    ssumseg[(size_t)seg * 1024 + f] = sm;
}

// ---------------------------------------------------------------- final projection (+bin combine)
__launch_bounds__(256)
__global__ void k_final(const float* __restrict__ smax, const float* __restrict__ ssg,
                        const float* __restrict__ Wf, const float* __restrict__ bfeat,
                        float* __restrict__ out)
{
    __shared__ float row[1024];
    int sb = blockIdx.x;             // s*4 + b, s in 0..62
    int s = sb >> 2, b = sb & 3;
    int nb = (s == 0) ? 1 : (s < 3) ? 2 : (s < 7) ? 4 : (s < 15) ? 8 : (s < 31) ? 16 : 32;
    int idxL = s - (nb - 1);
    int segc = 32 / nb;
    int seg0 = b * 32 + idxL * segc;
    float inv = 1.f / (float)(64 * segc);
    for (int c = threadIdx.x; c < 1024; c += 256) {
        float mx = -INFINITY, sm = 0.f;
        for (int t = 0; t < segc; ++t) {
            mx = fmaxf(mx, smax[(size_t)(seg0 + t) * 1024 + c]);
            sm += ssg[(size_t)(seg0 + t) * 1024 + c];
        }
        row[c] = mx + sm * inv;
    }
    __syncthreads();
    int o = threadIdx.x;
    const float* w = Wf + (size_t)o * 1024;
    float acc = 0.f;
    for (int fb = 0; fb < 1024; fb += 4) {
        float4 w4 = *(const float4*)&w[fb];
        acc = fmaf(row[fb + 0], w4.x, acc);
        acc = fmaf(row[fb + 1], w4.y, acc);
        acc = fmaf(row[fb + 2], w4.z, acc);
        acc = fmaf(row[fb + 3], w4.w, acc);
    }
    out[(size_t)sb * 256 + o] = acc + bfeat[o];
}

// ================================================================ launch
extern "C" void kernel_launch(void* const* d_in, const int* in_sizes, int n_in,
                              void* d_out, int out_size, void* d_ws, size_t ws_size,
                              hipStream_t stream)
{
    const float* x  = (const float*)d_in[0];
    const float* W1 = (const float*)d_in[1];
    const float* g1 = (const float*)d_in[2];
    const float* b1 = (const float*)d_in[3];
    const float* W2 = (const float*)d_in[4];
    const float* g2 = (const float*)d_in[5];
    const float* b2 = (const float*)d_in[6];
    const float* W3 = (const float*)d_in[7];
    const float* g3 = (const float*)d_in[8];
    const float* b3 = (const float*)d_in[9];
    const float* W4 = (const float*)d_in[10];
    const float* g4 = (const float*)d_in[11];
    const float* b4 = (const float*)d_in[12];
    const float* W5 = (const float*)d_in[13];
    const float* g5 = (const float*)d_in[14];
    const float* b5 = (const float*)d_in[15];
    const float* Wf = (const float*)d_in[16];
    const float* bfeat = (const float*)d_in[17];
    float* out = (float*)d_out;
    float* ws  = (float*)d_ws;

    // workspace layout (floats), total 17,424,896 = 69.7 MB
    float* xt1   = ws + 0;            // 24576
    int*   idx   = (int*)(ws + 24576);// 163840
    float* xx    = ws + 188416;       // 8192
    float* xc    = ws + 196608;       // 8192*512
    float* hmax  = ws + 4390912;      // 8192*256
    float* hmin  = ws + 6488064;      // 8192*256
    float* stats = ws + 8585216;      // 98304 (L1@0 L2@8192 L3@16384 L4@32768 L5@65536)
    float* smax  = ws + 8683520;      // 128*1024
    float* ssg   = ws + 8814592;      // 128*1024
    float* wc    = ws + 8945664;      // 90624 (L1@0 L2@384 L3@8576 L4@24960)
    float* big   = ws + 9036288;      // 8,388,608 (D2 | gtab+dtab | h5)
    float* gtab  = big;               // up to 8192*256
    float* dtab  = big + 2097152;     // up to 8192*256

    hipMemsetAsync(stats, 0, 98304 * sizeof(float), stream);
    k_transpose<<<32, 256, 0, stream>>>(x, xt1, xx);
    k_prepw_all<<<354, 256, 0, stream>>>(W1, W2, W3, W4, wc);

    const float invMk = 1.f / (float)(BN_ROWS * KNN);

    // ------------- layer 1: C=3, O=64
    {
        float* ss = stats + 0;
        for (int c = 0; c < 2; ++c) {
            k_mm128<MODE_DIST, false><<<dim3(16, 16, 2), 256, 0, stream>>>(xt1, 3, nullptr, 0, xx, 2*c, big, nullptr, N_PTS, 3);
            k_select<<<1024, 256, 0, stream>>>(big, 2*c, idx);
        }
        k_mm128<MODE_GD, false><<<dim3(1, 64, 1), 256, 0, stream>>>(xt1, 3, wc, 3, nullptr, 0, gtab, dtab, 128, 3);
        k_gather<64, 8><<<256, 256, 0, stream>>>(gtab, dtab, idx, hmax, hmin, ss, ss + 4096);
        k_normalize<64, true><<<512, 256, 0, stream>>>(hmax, hmin, ss, ss + 4096, g1, b1, invMk, xc + 0, xx);
    }
    // ------------- layer 2: C=64, O=64
    {
        float* ss = stats + 8192;
        for (int c = 0; c < 2; ++c) {
            k_mm128<MODE_DIST, true><<<dim3(16, 16, 2), 256, 0, stream>>>(xc + 0, 512, nullptr, 0, xx, 2*c, big, nullptr, N_PTS, 64);
            k_select<<<1024, 256, 0, stream>>>(big, 2*c, idx);
        }
        k_mm128<MODE_GD, true><<<dim3(1, 64, 1), 256, 0, stream>>>(xc + 0, 512, wc + 384, 64, nullptr, 0, gtab, dtab, 128, 64);
        k_gather<64, 8><<<256, 256, 0, stream>>>(gtab, dtab, idx, hmax, hmin, ss, ss + 4096);
        k_normalize<64, true><<<512, 256, 0, stream>>>(hmax, hmin, ss, ss + 4096, g2, b2, invMk, xc + 64, xx);
    }
    // ------------- layer 3: C=64, O=128
    {
        float* ss = stats + 16384;
        for (int c = 0; c < 2; ++c) {
            k_mm128<MODE_DIST, true><<<dim3(16, 16, 2), 256, 0, stream>>>(xc + 64, 512, nullptr, 0, xx, 2*c, big, nullptr, N_PTS, 64);
            k_select<<<1024, 256, 0, stream>>>(big, 2*c, idx);
        }
        k_mm128<MODE_GD, true><<<dim3(2, 64, 1), 256, 0, stream>>>(xc + 64, 512, wc + 8576, 64, nullptr, 0, gtab, dtab, 256, 64);
        k_gather<128, 8><<<512, 256, 0, stream>>>(gtab, dtab, idx, hmax, hmin, ss, ss + 8192);
        k_normalize<128, true><<<512, 256, 0, stream>>>(hmax, hmin, ss, ss + 8192, g3, b3, invMk, xc + 128, xx);
    }
    // ------------- layer 4: C=128, O=256
    {
        float* ss = stats + 32768;
        for (int c = 0; c < 2; ++c) {
            k_mm128<MODE_DIST, true><<<dim3(16, 16, 2), 256, 0, stream>>>(xc + 128, 512, nullptr, 0, xx, 2*c, big, nullptr, N_PTS, 128);
            k_select<<<1024, 256, 0, stream>>>(big, 2*c, idx);
        }
        k_mm128<MODE_GD, true><<<dim3(4, 64, 1), 256, 0, stream>>>(xc + 128, 512, wc + 24960, 128, nullptr, 0, gtab, dtab, 512, 128);
        k_gather<256, 8><<<1024, 256, 0, stream>>>(gtab, dtab, idx, hmax, hmin, ss, ss + 16384);
        k_normalize<256, false><<<512, 256, 0, stream>>>(hmax, hmin, ss, ss + 16384, g4, b4, invMk, xc + 256, xx);
    }
    // ------------- layer 5: h5 = xc @ W5^T, split-K=2 atomic accumulate
    {
        float* ss = stats + 65536;
        hipMemsetAsync(big, 0, 8388608 * sizeof(float), stream);
        k_mm128<MODE_ACC, true><<<dim3(8, 64, 2), 256, 0, stream>>>(xc, 512, W5, 512, nullptr, 0, big, nullptr, 1024, 512);
        k_stats5<<<dim3(16, 4), 256, 0, stream>>>(big, ss, ss + 16384);
        k_seg<<<dim3(128, 4), 256, 0, stream>>>(big, ss, ss + 16384, g5, b5, smax, ssg);
        k_final<<<252, 256, 0, stream>>>(smax, ssg, Wf, bfeat, out);
    }
}

// Round 6
// 783.975 us; speedup vs baseline: 1.3182x; 1.3182x over previous
//
#include <hip/hip_runtime.h>
#include <hip/hip_bf16.h>
#include <cstdint>
#include <cstddef>

#define B_SZ   4
#define N_PTS  2048
#define KNN    20
#define BN_ROWS (B_SZ * N_PTS)
#define EPSV   1e-5f
#define SLOPEV 0.2f

#define MODE_GD   0
#define MODE_DIST 1

typedef __attribute__((ext_vector_type(8))) short bf16x8;
typedef __attribute__((ext_vector_type(4))) float f32x4;

// ---------------------------------------------------------------- transpose + xx
__global__ void k_transpose(const float* __restrict__ x, float* __restrict__ xt,
                            float* __restrict__ xx)
{
    int i = blockIdx.x * 256 + threadIdx.x;
    if (i >= BN_ROWS) return;
    int b = i >> 11, n = i & 2047;
    float v0 = x[((b * 3 + 0) << 11) + n];
    float v1 = x[((b * 3 + 1) << 11) + n];
    float v2 = x[((b * 3 + 2) << 11) + n];
    xt[i * 3 + 0] = v0; xt[i * 3 + 1] = v1; xt[i * 3 + 2] = v2;
    xx[i] = fmaf(v0, v0, fmaf(v1, v1, v2 * v2));
}

// ---------------------------------------------------------------- batched weight prep
// L1..L4: W (O,2C) -> [W1 | W2-W1] f32 at fixed offsets; plus W5 -> bf16 copy.
__global__ void k_prepw_all(const float* __restrict__ W1, const float* __restrict__ W2,
                            const float* __restrict__ W3, const float* __restrict__ W4,
                            const float* __restrict__ W5,
                            float* __restrict__ wc, __hip_bfloat16* __restrict__ w5h)
{
    int i = blockIdx.x * 256 + threadIdx.x;
    if (i >= 614784) return;
    if (i >= 90496) {                       // W5 (1024x512) -> bf16
        int e = i - 90496;
        w5h[e] = __float2bfloat16(W5[e]);
        return;
    }
    const float* W; int O, C, off;
    if      (i < 384)   { W = W1; O = 64;  C = 3;   off = 0; }
    else if (i < 8576)  { W = W2; O = 64;  C = 64;  off = 384; }
    else if (i < 24960) { W = W3; O = 128; C = 64;  off = 8576; }
    else                { W = W4; O = 256; C = 128; off = 24960; }
    int e = i - off, j = e / C, c = e - j * C;
    float v;
    if (j < O) v = W[j * 2 * C + c];
    else { int jo = j - O; v = W[jo * 2 * C + C + c] - W[jo * 2 * C + c]; }
    wc[i] = v;
}

// ---------------------------------------------------------------- 128x128 f32 GEMM core
// MODE_GD  : C = A(MxK) @ Bm(NnxK)^T, cols < Nn/2 -> C1 (gtab), rest -> C2 (dtab)
// MODE_DIST: per batch z: D2 = 2*A A^T - xx_i - xx_j, diagonal forced to 0
#define MM_BODY(kk) do {                                                          \
    float4 a0 = *(const float4*)&As[(kk) * LDT + ty * 4];                         \
    float4 a1 = *(const float4*)&As[(kk) * LDT + 64 + ty * 4];                    \
    float4 c0 = *(const float4*)&Bs[(kk) * LDT + tx * 4];                         \
    float4 c1 = *(const float4*)&Bs[(kk) * LDT + 64 + tx * 4];                    \
    float av[2][4] = {{a0.x,a0.y,a0.z,a0.w},{a1.x,a1.y,a1.z,a1.w}};               \
    float bw[2][4] = {{c0.x,c0.y,c0.z,c0.w},{c1.x,c1.y,c1.z,c1.w}};               \
    _Pragma("unroll") for (int ih = 0; ih < 2; ++ih)                              \
    _Pragma("unroll") for (int jh = 0; jh < 2; ++jh)                              \
    _Pragma("unroll") for (int ii = 0; ii < 4; ++ii)                              \
    _Pragma("unroll") for (int jj = 0; jj < 4; ++jj)                              \
        acc[ih][jh][ii][jj] = fmaf(av[ih][ii], bw[jh][jj], acc[ih][jh][ii][jj]);  \
} while (0)

template<int MODE, bool VEC>
__launch_bounds__(256)
__global__ void k_mm128(const float* __restrict__ A, int lda,
                        const float* __restrict__ Bm, int ldb,
                        const float* __restrict__ xx, int b0,
                        float* __restrict__ C1, float* __restrict__ C2,
                        int Nn, int Kd)
{
    constexpr int LDT = 132;
    __shared__ float As[32 * LDT];
    __shared__ float Bs[32 * LDT];
    const int tid = threadIdx.x;
    const int tx  = tid & 15;
    const int ty  = tid >> 4;
    const int m0  = blockIdx.y * 128;
    const int n0  = blockIdx.x * 128;

    const float* Ab;
    const float* Bb;
    int ldbe;
    if constexpr (MODE == MODE_DIST) {
        const int b = b0 + blockIdx.z;
        Ab = A + (size_t)b * N_PTS * lda;
        Bb = Ab;
        ldbe = lda;
    } else {
        Ab = A; Bb = Bm; ldbe = ldb;
    }

    float acc[2][2][4][4] = {};

    for (int k0 = 0; k0 < Kd; k0 += 32) {
        #pragma unroll
        for (int r = 0; r < 4; ++r) {
            int e = r * 256 + tid, row = e >> 3, kq = e & 7;
            if constexpr (VEC) {
                float4 v = *(const float4*)&Ab[(size_t)(m0 + row) * lda + k0 + kq * 4];
                As[(kq * 4 + 0) * LDT + row] = v.x;
                As[(kq * 4 + 1) * LDT + row] = v.y;
                As[(kq * 4 + 2) * LDT + row] = v.z;
                As[(kq * 4 + 3) * LDT + row] = v.w;
            } else {
                #pragma unroll
                for (int j = 0; j < 4; ++j) {
                    int kg = k0 + kq * 4 + j;
                    As[(kq * 4 + j) * LDT + row] =
                        (kg < Kd) ? Ab[(size_t)(m0 + row) * lda + kg] : 0.f;
                }
            }
        }
        #pragma unroll
        for (int r = 0; r < 4; ++r) {
            int e = r * 256 + tid, row = e >> 3, kq = e & 7;
            if constexpr (VEC) {
                float4 v = *(const float4*)&Bb[(size_t)(n0 + row) * ldbe + k0 + kq * 4];
                Bs[(kq * 4 + 0) * LDT + row] = v.x;
                Bs[(kq * 4 + 1) * LDT + row] = v.y;
                Bs[(kq * 4 + 2) * LDT + row] = v.z;
                Bs[(kq * 4 + 3) * LDT + row] = v.w;
            } else {
                #pragma unroll
                for (int j = 0; j < 4; ++j) {
                    int kg = k0 + kq * 4 + j;
                    Bs[(kq * 4 + j) * LDT + row] =
                        (kg < Kd) ? Bb[(size_t)(n0 + row) * ldbe + kg] : 0.f;
                }
            }
        }
        __syncthreads();

        int klen = Kd - k0; if (klen > 32) klen = 32;
        if (klen == 32) {
            #pragma unroll 8
            for (int kk = 0; kk < 32; ++kk) MM_BODY(kk);
        } else {
            for (int kk = 0; kk < klen; ++kk) MM_BODY(kk);
        }
        __syncthreads();
    }

    if constexpr (MODE == MODE_DIST) {
        const int b = b0 + blockIdx.z;
        const float* xxb = xx + b * N_PTS;
        float xj[2][4];
        #pragma unroll
        for (int jh = 0; jh < 2; ++jh) {
            float4 v = *(const float4*)&xxb[n0 + jh * 64 + tx * 4];
            xj[jh][0] = v.x; xj[jh][1] = v.y; xj[jh][2] = v.z; xj[jh][3] = v.w;
        }
        #pragma unroll
        for (int ih = 0; ih < 2; ++ih)
            #pragma unroll
            for (int i = 0; i < 4; ++i) {
                int gi = m0 + ih * 64 + ty * 4 + i;
                float xi = xxb[gi];
                size_t base = ((size_t)blockIdx.z * N_PTS + gi) * N_PTS;
                #pragma unroll
                for (int jh = 0; jh < 2; ++jh) {
                    int gj = n0 + jh * 64 + tx * 4;
                    float4 v;
                    v.x = 2.f * acc[ih][jh][i][0] - xi - xj[jh][0];
                    v.y = 2.f * acc[ih][jh][i][1] - xi - xj[jh][1];
                    v.z = 2.f * acc[ih][jh][i][2] - xi - xj[jh][2];
                    v.w = 2.f * acc[ih][jh][i][3] - xi - xj[jh][3];
                    if (m0 == n0) {                 // diagonal block only
                        if (gi == gj + 0) v.x = 0.f;
                        if (gi == gj + 1) v.y = 0.f;
                        if (gi == gj + 2) v.z = 0.f;
                        if (gi == gj + 3) v.w = 0.f;
                    }
                    *(float4*)&C1[base + gj] = v;
                }
            }
    } else {  // MODE_GD
        const int Oo = Nn >> 1;
        #pragma unroll
        for (int ih = 0; ih < 2; ++ih)
            #pragma unroll
            for (int i = 0; i < 4; ++i) {
                int row = m0 + ih * 64 + ty * 4 + i;
                #pragma unroll
                for (int jh = 0; jh < 2; ++jh) {
                    int colg = n0 + jh * 64 + tx * 4;
                    float4 v = make_float4(acc[ih][jh][i][0], acc[ih][jh][i][1],
                                           acc[ih][jh][i][2], acc[ih][jh][i][3]);
                    if (colg < Oo) *(float4*)&C1[(size_t)row * Oo + colg] = v;
                    else           *(float4*)&C2[(size_t)row * Oo + colg - Oo] = v;
                }
            }
    }
}

// ---------------------------------------------------------------- bf16 MFMA GEMM (layer 5)
// C(8192x1024) = A(8192x512) @ B(1024x512)^T, A/B bf16, C f32.
// 128x128 tile, 4 waves, each wave 64x64 via 4x4 mfma_f32_16x16x32_bf16, BK=64.
__launch_bounds__(256)
__global__ void k_gemm5(const unsigned short* __restrict__ Ah,
                        const unsigned short* __restrict__ Bh,
                        float* __restrict__ Cf)
{
    constexpr int LDA = 72;                    // bf16 elems per LDS row (+8 pad)
    __shared__ unsigned short As[128 * LDA];
    __shared__ unsigned short Bs[128 * LDA];
    const int tid  = threadIdx.x;
    const int lane = tid & 63;
    const int w    = tid >> 6;
    const int wr   = w >> 1, wcl = w & 1;
    const int quad = lane >> 4;
    const int l16  = lane & 15;
    const int m0 = blockIdx.y * 128;
    const int n0 = blockIdx.x * 128;

    f32x4 acc[4][4] = {};

    for (int k0 = 0; k0 < 512; k0 += 64) {
        #pragma unroll
        for (int r = 0; r < 4; ++r) {
            int e = r * 256 + tid, row = e >> 3, kq = e & 7;
            *(uint4*)&As[row * LDA + kq * 8] =
                *(const uint4*)&Ah[(size_t)(m0 + row) * 512 + k0 + kq * 8];
        }
        #pragma unroll
        for (int r = 0; r < 4; ++r) {
            int e = r * 256 + tid, row = e >> 3, kq = e & 7;
            *(uint4*)&Bs[row * LDA + kq * 8] =
                *(const uint4*)&Bh[(size_t)(n0 + row) * 512 + k0 + kq * 8];
        }
        __syncthreads();
        #pragma unroll
        for (int kk = 0; kk < 64; kk += 32) {
            bf16x8 af[4], bfr[4];
            #pragma unroll
            for (int i = 0; i < 4; ++i)
                af[i] = *(const bf16x8*)&As[(wr * 64 + i * 16 + l16) * LDA + kk + quad * 8];
            #pragma unroll
            for (int j = 0; j < 4; ++j)
                bfr[j] = *(const bf16x8*)&Bs[(wcl * 64 + j * 16 + l16) * LDA + kk + quad * 8];
            #pragma unroll
            for (int i = 0; i < 4; ++i)
                #pragma unroll
                for (int j = 0; j < 4; ++j)
                    acc[i][j] = __builtin_amdgcn_mfma_f32_16x16x32_bf16(af[i], bfr[j], acc[i][j], 0, 0, 0);
        }
        __syncthreads();
    }

    #pragma unroll
    for (int i = 0; i < 4; ++i) {
        int rbase = m0 + wr * 64 + i * 16 + quad * 4;
        #pragma unroll
        for (int j = 0; j < 4; ++j) {
            int col = n0 + wcl * 64 + j * 16 + l16;
            #pragma unroll
            for (int r = 0; r < 4; ++r)
                Cf[(size_t)(rbase + r) * 1024 + col] = acc[i][j][r];
        }
    }
}

// ---------------------------------------------------------------- top-20 select
__launch_bounds__(256)
__global__ void k_select(const float* __restrict__ D2, int b0, int* __restrict__ idx_out)
{
    const int lane = threadIdx.x & 63;
    const int w    = threadIdx.x >> 6;
    const int qloc = blockIdx.x * 4 + w;
    const int bl   = qloc >> 11;
    const int n    = qloc & 2047;
    const float* row = D2 + (size_t)qloc * N_PTS;

    unsigned key[32];
    #pragma unroll
    for (int c = 0; c < 8; ++c) {
        float4 v = *(const float4*)&row[c * 256 + lane * 4];
        float vv[4] = {v.x, v.y, v.z, v.w};
        #pragma unroll
        for (int r = 0; r < 4; ++r) {
            unsigned u = __float_as_uint(vv[r]);
            key[c * 4 + r] = ((int)u >= 0) ? (u | 0x80000000u) : ~u;
        }
    }

    unsigned lo = 0u, hi = 0xFFFFFFFFu;
    while (lo < hi) {
        unsigned mid = lo + ((hi - lo) >> 1);
        int cnt = 0;
        #pragma unroll
        for (int e = 0; e < 32; ++e) cnt += (key[e] > mid) ? 1 : 0;
        #pragma unroll
        for (int s = 32; s >= 1; s >>= 1) cnt += __shfl_xor(cnt, s, 64);
        cnt = __builtin_amdgcn_readfirstlane(cnt);
        if (cnt < KNN) hi = mid; else lo = mid + 1;
    }
    const unsigned T = lo;

    int* outp = idx_out + (size_t)((b0 + bl) * N_PTS + n) * KNN;
    const unsigned long long ltmask = (lane == 0) ? 0ull : (~0ull >> (64 - lane));
    int base = 0;
    #pragma unroll
    for (int e = 0; e < 32; ++e) {
        bool p = key[e] > T;
        unsigned long long m = __ballot(p);
        if (p) {
            int pos = base + __popcll(m & ltmask);
            outp[pos] = (e >> 2) * 256 + lane * 4 + (e & 3);
        }
        base += __popcll(m);
    }
    for (int e = 0; e < 32 && base < KNN; ++e) {
        bool p = key[e] == T;
        unsigned long long m = __ballot(p);
        if (p) {
            int pos = base + __popcll(m & ltmask);
            if (pos < KNN) outp[pos] = (e >> 2) * 256 + lane * 4 + (e & 3);
        }
        base += __popcll(m);
    }
}

// ---------------------------------------------------------------- gather + stats
template<int O, int NSEQ>
__launch_bounds__(256)
__global__ void k_gather(const float* __restrict__ gtab, const float* __restrict__ dtab,
                         const int* __restrict__ idx,
                         float* __restrict__ hmax, float* __restrict__ hmin,
                         float* __restrict__ ssum, float* __restrict__ ssumsq)
{
    constexpr int NPB = 256 / O;
    const int grp = threadIdx.x / O;
    const int o   = threadIdx.x & (O - 1);
    float accS = 0.f, accS2 = 0.f;
    const int rowsPerBlock = NPB * NSEQ;
    for (int s = 0; s < NSEQ; ++s) {
        int row = blockIdx.x * rowsPerBlock + s * NPB + grp;
        const int* ip = idx + (size_t)row * KNN;
        int bbase = (row >> 11) << 11;
        float gmax = -INFINITY, gmin = INFINITY, gs = 0.f, gs2 = 0.f;
        for (int k = 0; k < KNN; ++k) {
            int nb = ip[k];
            float v = gtab[(size_t)(bbase + nb) * O + o];
            gmax = fmaxf(gmax, v);
            gmin = fminf(gmin, v);
            gs  += v;
            gs2  = fmaf(v, v, gs2);
        }
        float d = dtab[(size_t)row * O + o];
        hmax[(size_t)row * O + o] = gmax + d;
        hmin[(size_t)row * O + o] = gmin + d;
        accS  += gs + (float)KNN * d;
        accS2 += gs2 + 2.f * d * gs + (float)KNN * d * d;
    }
    int bank = blockIdx.x & 63;
    atomicAdd(&ssum[bank * O + o], accS);
    atomicAdd(&ssumsq[bank * O + o], accS2);
}

// ---------------------------------------------------------------- normalize (+BN finalize, +xx, +bf16 mirror)
template<int O, bool WRITE_XX>
__launch_bounds__(256)
__global__ void k_normalize(const float* __restrict__ hmax, const float* __restrict__ hmin,
                            const float* __restrict__ ssum, const float* __restrict__ ssumsq,
                            const float* __restrict__ gamma, const float* __restrict__ beta,
                            float invM, float* __restrict__ xcs,
                            __hip_bfloat16* __restrict__ xch, float* __restrict__ xx)
{
    const int tid = threadIdx.x;
    const int o   = tid & (O - 1);
    float s = 0.f, s2 = 0.f;
    #pragma unroll 8
    for (int bk = 0; bk < 64; ++bk) { s += ssum[bk * O + o]; s2 += ssumsq[bk * O + o]; }
    float mean = s * invM;
    float var  = fmaf(-mean, mean, s2 * invM);
    float sc   = gamma[o] * rsqrtf(var + EPSV);
    float sh   = beta[o] - mean * sc;

    constexpr int R = 256 / O;
    const int rloc = tid / O;
    __shared__ float part[4];
    const int ngroups = BN_ROWS / R;
    for (int gidx = blockIdx.x; gidx < ngroups; gidx += gridDim.x) {
        int row = gidx * R + rloc;
        size_t i = (size_t)row * O + o;
        float h = (sc >= 0.f) ? hmax[i] : hmin[i];
        float y = fmaf(h, sc, sh);
        y = (y >= 0.f) ? y : SLOPEV * y;
        xcs[(size_t)row * 512 + o] = y;
        xch[(size_t)row * 512 + o] = __float2bfloat16(y);
        if constexpr (WRITE_XX) {
            float p = y * y;
            #pragma unroll
            for (int sft = 32; sft >= 1; sft >>= 1) p += __shfl_xor(p, sft, 64);
            if constexpr (O == 64) {
                if ((tid & 63) == 0) xx[row] = p;
            } else {
                if ((tid & 63) == 0) part[tid >> 6] = p;
                __syncthreads();
                if constexpr (O == 128) {
                    if (tid < 2) xx[gidx * R + tid] = part[2 * tid] + part[2 * tid + 1];
                } else {
                    if (tid == 0) xx[gidx * R] = (part[0] + part[1]) + (part[2] + part[3]);
                }
                __syncthreads();
            }
        }
    }
}

// ---------------------------------------------------------------- layer-5 stats (16 banks)
__global__ void k_stats5(const float* __restrict__ h, float* __restrict__ ssum, float* __restrict__ ssumsq)
{
    int o  = blockIdx.y * 256 + threadIdx.x;
    int r0 = blockIdx.x * 512;
    float s = 0.f, s2 = 0.f;
    for (int r = 0; r < 512; ++r) {
        float v = h[(size_t)(r0 + r) * 1024 + o];
        s += v; s2 = fmaf(v, v, s2);
    }
    ssum[blockIdx.x * 1024 + o]   = s;
    ssumsq[blockIdx.x * 1024 + o] = s2;
}

// ---------------------------------------------------------------- normalize+lrelu + 64-seg max/sum (+finalize)
__global__ void k_seg(const float* __restrict__ h,
                      const float* __restrict__ ssum, const float* __restrict__ ssumsq,
                      const float* __restrict__ gamma, const float* __restrict__ beta,
                      float* __restrict__ smax, float* __restrict__ ssumseg)
{
    int f = blockIdx.y * 256 + threadIdx.x;
    float s = 0.f, s2 = 0.f;
    #pragma unroll
    for (int bk = 0; bk < 16; ++bk) { s += ssum[bk * 1024 + f]; s2 += ssumsq[bk * 1024 + f]; }
    const float invM = 1.f / (float)BN_ROWS;
    float mean = s * invM;
    float var  = fmaf(-mean, mean, s2 * invM);
    float sc   = gamma[f] * rsqrtf(var + EPSV);
    float sh   = beta[f] - mean * sc;

    int seg = blockIdx.x;
    float mx = -INFINITY, sm = 0.f;
    int n0 = seg * 64;
    for (int i = 0; i < 64; ++i) {
        float v = fmaf(h[(size_t)(n0 + i) * 1024 + f], sc, sh);
        v = (v >= 0.f) ? v : SLOPEV * v;
        mx = fmaxf(mx, v); sm += v;
    }
    smax[(size_t)seg * 1024 + f]    = mx;
    ssumseg[(size_t)seg * 1024 + f] = sm;
}

// ---------------------------------------------------------------- final projection (+bin combine)
__launch_bounds__(256)
__global__ void k_final(const float* __restrict__ smax, const float* __restrict__ ssg,
                        const float* __restrict__ Wf, const float* __restrict__ bfeat,
                        float* __restrict__ out)
{
    __shared__ float row[1024];
    int sb = blockIdx.x;             // s*4 + b, s in 0..62
    int s = sb >> 2, b = sb & 3;
    int nb = (s == 0) ? 1 : (s < 3) ? 2 : (s < 7) ? 4 : (s < 15) ? 8 : (s < 31) ? 16 : 32;
    int idxL = s - (nb - 1);
    int segc = 32 / nb;
    int seg0 = b * 32 + idxL * segc;
    float inv = 1.f / (float)(64 * segc);
    for (int c = threadIdx.x; c < 1024; c += 256) {
        float mx = -INFINITY, sm = 0.f;
        for (int t = 0; t < segc; ++t) {
            mx = fmaxf(mx, smax[(size_t)(seg0 + t) * 1024 + c]);
            sm += ssg[(size_t)(seg0 + t) * 1024 + c];
        }
        row[c] = mx + sm * inv;
    }
    __syncthreads();
    int o = threadIdx.x;
    const float* w = Wf + (size_t)o * 1024;
    float acc = 0.f;
    for (int fb = 0; fb < 1024; fb += 4) {
        float4 w4 = *(const float4*)&w[fb];
        acc = fmaf(row[fb + 0], w4.x, acc);
        acc = fmaf(row[fb + 1], w4.y, acc);
        acc = fmaf(row[fb + 2], w4.z, acc);
        acc = fmaf(row[fb + 3], w4.w, acc);
    }
    out[(size_t)sb * 256 + o] = acc + bfeat[o];
}

// ================================================================ launch
extern "C" void kernel_launch(void* const* d_in, const int* in_sizes, int n_in,
                              void* d_out, int out_size, void* d_ws, size_t ws_size,
                              hipStream_t stream)
{
    const float* x  = (const float*)d_in[0];
    const float* W1 = (const float*)d_in[1];
    const float* g1 = (const float*)d_in[2];
    const float* b1 = (const float*)d_in[3];
    const float* W2 = (const float*)d_in[4];
    const float* g2 = (const float*)d_in[5];
    const float* b2 = (const float*)d_in[6];
    const float* W3 = (const float*)d_in[7];
    const float* g3 = (const float*)d_in[8];
    const float* b3 = (const float*)d_in[9];
    const float* W4 = (const float*)d_in[10];
    const float* g4 = (const float*)d_in[11];
    const float* b4 = (const float*)d_in[12];
    const float* W5 = (const float*)d_in[13];
    const float* g5 = (const float*)d_in[14];
    const float* b5 = (const float*)d_in[15];
    const float* Wf = (const float*)d_in[16];
    const float* bfeat = (const float*)d_in[17];
    float* out = (float*)d_out;
    float* ws  = (float*)d_ws;

    // workspace layout (floats), total 19,784,192 = 79.1 MB
    float* xt1   = ws + 0;            // 24576
    int*   idx   = (int*)(ws + 24576);// 163840
    float* xx    = ws + 188416;       // 8192
    float* xc    = ws + 196608;       // 8192*512
    float* hmax  = ws + 4390912;      // 8192*256
    float* hmin  = ws + 6488064;      // 8192*256
    float* stats = ws + 8585216;      // 98304 (L1@0 L2@8192 L3@16384 L4@32768 L5@65536)
    float* smax  = ws + 8683520;      // 128*1024
    float* ssg   = ws + 8814592;      // 128*1024
    float* wc    = ws + 8945664;      // 90624 (L1@0 L2@384 L3@8576 L4@24960)
    float* big   = ws + 9036288;      // 8,388,608 (D2 | gtab+dtab | h5)
    float* gtab  = big;               // up to 8192*256
    float* dtab  = big + 2097152;     // up to 8192*256
    __hip_bfloat16* xch = (__hip_bfloat16*)(ws + 17424896);  // 8192*512 bf16 (2,097,152 f32 slots)
    __hip_bfloat16* w5h = (__hip_bfloat16*)(ws + 19522048);  // 1024*512 bf16 (262,144 f32 slots)

    hipMemsetAsync(stats, 0, 98304 * sizeof(float), stream);
    k_transpose<<<32, 256, 0, stream>>>(x, xt1, xx);
    k_prepw_all<<<2402, 256, 0, stream>>>(W1, W2, W3, W4, W5, wc, w5h);

    const float invMk = 1.f / (float)(BN_ROWS * KNN);

    // ------------- layer 1: C=3, O=64
    {
        float* ss = stats + 0;
        for (int c = 0; c < 2; ++c) {
            k_mm128<MODE_DIST, false><<<dim3(16, 16, 2), 256, 0, stream>>>(xt1, 3, nullptr, 0, xx, 2*c, big, nullptr, N_PTS, 3);
            k_select<<<1024, 256, 0, stream>>>(big, 2*c, idx);
        }
        k_mm128<MODE_GD, false><<<dim3(1, 64, 1), 256, 0, stream>>>(xt1, 3, wc, 3, nullptr, 0, gtab, dtab, 128, 3);
        k_gather<64, 8><<<256, 256, 0, stream>>>(gtab, dtab, idx, hmax, hmin, ss, ss + 4096);
        k_normalize<64, true><<<512, 256, 0, stream>>>(hmax, hmin, ss, ss + 4096, g1, b1, invMk, xc + 0, xch + 0, xx);
    }
    // ------------- layer 2: C=64, O=64
    {
        float* ss = stats + 8192;
        for (int c = 0; c < 2; ++c) {
            k_mm128<MODE_DIST, true><<<dim3(16, 16, 2), 256, 0, stream>>>(xc + 0, 512, nullptr, 0, xx, 2*c, big, nullptr, N_PTS, 64);
            k_select<<<1024, 256, 0, stream>>>(big, 2*c, idx);
        }
        k_mm128<MODE_GD, true><<<dim3(1, 64, 1), 256, 0, stream>>>(xc + 0, 512, wc + 384, 64, nullptr, 0, gtab, dtab, 128, 64);
        k_gather<64, 8><<<256, 256, 0, stream>>>(gtab, dtab, idx, hmax, hmin, ss, ss + 4096);
        k_normalize<64, true><<<512, 256, 0, stream>>>(hmax, hmin, ss, ss + 4096, g2, b2, invMk, xc + 64, xch + 64, xx);
    }
    // ------------- layer 3: C=64, O=128
    {
        float* ss = stats + 16384;
        for (int c = 0; c < 2; ++c) {
            k_mm128<MODE_DIST, true><<<dim3(16, 16, 2), 256, 0, stream>>>(xc + 64, 512, nullptr, 0, xx, 2*c, big, nullptr, N_PTS, 64);
            k_select<<<1024, 256, 0, stream>>>(big, 2*c, idx);
        }
        k_mm128<MODE_GD, true><<<dim3(2, 64, 1), 256, 0, stream>>>(xc + 64, 512, wc + 8576, 64, nullptr, 0, gtab, dtab, 256, 64);
        k_gather<128, 8><<<512, 256, 0, stream>>>(gtab, dtab, idx, hmax, hmin, ss, ss + 8192);
        k_normalize<128, true><<<512, 256, 0, stream>>>(hmax, hmin, ss, ss + 8192, g3, b3, invMk, xc + 128, xch + 128, xx);
    }
    // ------------- layer 4: C=128, O=256
    {
        float* ss = stats + 32768;
        for (int c = 0; c < 2; ++c) {
            k_mm128<MODE_DIST, true><<<dim3(16, 16, 2), 256, 0, stream>>>(xc + 128, 512, nullptr, 0, xx, 2*c, big, nullptr, N_PTS, 128);
            k_select<<<1024, 256, 0, stream>>>(big, 2*c, idx);
        }
        k_mm128<MODE_GD, true><<<dim3(4, 64, 1), 256, 0, stream>>>(xc + 128, 512, wc + 24960, 128, nullptr, 0, gtab, dtab, 512, 128);
        k_gather<256, 8><<<1024, 256, 0, stream>>>(gtab, dtab, idx, hmax, hmin, ss, ss + 16384);
        k_normalize<256, false><<<512, 256, 0, stream>>>(hmax, hmin, ss, ss + 16384, g4, b4, invMk, xc + 256, xch + 256, xx);
    }
    // ------------- layer 5: h5 = xch @ w5h^T via bf16 MFMA, then stats/seg/final
    {
        float* ss = stats + 65536;
        k_gemm5<<<dim3(8, 64), 256, 0, stream>>>((const unsigned short*)xch, (const unsigned short*)w5h, big);
        k_stats5<<<dim3(16, 4), 256, 0, stream>>>(big, ss, ss + 16384);
        k_seg<<<dim3(128, 4), 256, 0, stream>>>(big, ss, ss + 16384, g5, b5, smax, ssg);
        k_final<<<252, 256, 0, stream>>>(smax, ssg, Wf, bfeat, out);
    }
}

// Round 7
// 770.685 us; speedup vs baseline: 1.3409x; 1.0172x over previous
//
#include <hip/hip_runtime.h>
#include <hip/hip_bf16.h>
#include <cstdint>
#include <cstddef>

#define B_SZ   4
#define N_PTS  2048
#define KNN    20
#define BN_ROWS (B_SZ * N_PTS)
#define EPSV   1e-5f
#define SLOPEV 0.2f

#define MODE_GD   0
#define MODE_DIST 1

typedef __attribute__((ext_vector_type(8))) short bf16x8;
typedef __attribute__((ext_vector_type(4))) float f32x4;

// ---------------------------------------------------------------- transpose + xx
__global__ void k_transpose(const float* __restrict__ x, float* __restrict__ xt,
                            float* __restrict__ xx)
{
    int i = blockIdx.x * 256 + threadIdx.x;
    if (i >= BN_ROWS) return;
    int b = i >> 11, n = i & 2047;
    float v0 = x[((b * 3 + 0) << 11) + n];
    float v1 = x[((b * 3 + 1) << 11) + n];
    float v2 = x[((b * 3 + 2) << 11) + n];
    xt[i * 3 + 0] = v0; xt[i * 3 + 1] = v1; xt[i * 3 + 2] = v2;
    xx[i] = fmaf(v0, v0, fmaf(v1, v1, v2 * v2));
}

// ---------------------------------------------------------------- batched weight prep
__global__ void k_prepw_all(const float* __restrict__ W1, const float* __restrict__ W2,
                            const float* __restrict__ W3, const float* __restrict__ W4,
                            const float* __restrict__ W5,
                            float* __restrict__ wc, __hip_bfloat16* __restrict__ w5h)
{
    int i = blockIdx.x * 256 + threadIdx.x;
    if (i >= 614784) return;
    if (i >= 90496) {                       // W5 (1024x512) -> bf16
        int e = i - 90496;
        w5h[e] = __float2bfloat16(W5[e]);
        return;
    }
    const float* W; int O, C, off;
    if      (i < 384)   { W = W1; O = 64;  C = 3;   off = 0; }
    else if (i < 8576)  { W = W2; O = 64;  C = 64;  off = 384; }
    else if (i < 24960) { W = W3; O = 128; C = 64;  off = 8576; }
    else                { W = W4; O = 256; C = 128; off = 24960; }
    int e = i - off, j = e / C, c = e - j * C;
    float v;
    if (j < O) v = W[j * 2 * C + c];
    else { int jo = j - O; v = W[jo * 2 * C + C + c] - W[jo * 2 * C + c]; }
    wc[i] = v;
}

// ---------------------------------------------------------------- 128x64 GEMM core
// Tile 128(i) x 64(j): grid (Nj/64, M/128 [,z]). 2x the blocks of the old
// 128x128 => 4 blocks/CU (old kernel was grid-limited to 2). Per kk: 3
// ds_read_b128 per 32 fma.
// MODE_GD  : C = A(MxK) @ Bm(NnxK)^T, cols < Nn/2 -> C1 (gtab), rest -> C2 (dtab)
// MODE_DIST: per batch z: D2 = 2*A A^T - xx_i - xx_j, diagonal forced to 0
#define MM_BODY(kk) do {                                                          \
    float4 a0 = *(const float4*)&As[(kk) * LDA_ + ty * 4];                        \
    float4 a1 = *(const float4*)&As[(kk) * LDA_ + 64 + ty * 4];                   \
    float4 bq = *(const float4*)&Bs[(kk) * LDB_ + tx * 4];                        \
    float av[2][4] = {{a0.x,a0.y,a0.z,a0.w},{a1.x,a1.y,a1.z,a1.w}};               \
    float bw[4] = {bq.x, bq.y, bq.z, bq.w};                                       \
    _Pragma("unroll") for (int ih = 0; ih < 2; ++ih)                              \
    _Pragma("unroll") for (int ii = 0; ii < 4; ++ii)                              \
    _Pragma("unroll") for (int jj = 0; jj < 4; ++jj)                              \
        acc[ih][ii][jj] = fmaf(av[ih][ii], bw[jj], acc[ih][ii][jj]);              \
} while (0)

template<int MODE, bool VEC>
__launch_bounds__(256)
__global__ void k_mm128(const float* __restrict__ A, int lda,
                        const float* __restrict__ Bm, int ldb,
                        const float* __restrict__ xx, int b0,
                        float* __restrict__ C1, float* __restrict__ C2,
                        int Nn, int Kd)
{
    constexpr int LDA_ = 132;     // 128 + 4 pad
    constexpr int LDB_ = 68;      // 64 + 4 pad
    __shared__ float As[32 * LDA_];
    __shared__ float Bs[32 * LDB_];
    const int tid = threadIdx.x;
    const int tx  = tid & 15;     // j group (16 x 4 = 64)
    const int ty  = tid >> 4;     // i group (16 x 8 = 128, split 4+4)
    const int m0  = blockIdx.y * 128;
    const int n0  = blockIdx.x * 64;

    const float* Ab;
    const float* Bb;
    int ldbe;
    if constexpr (MODE == MODE_DIST) {
        const int b = b0 + blockIdx.z;
        Ab = A + (size_t)b * N_PTS * lda;
        Bb = Ab;
        ldbe = lda;
    } else {
        Ab = A; Bb = Bm; ldbe = ldb;
    }

    float acc[2][4][4] = {};

    for (int k0 = 0; k0 < Kd; k0 += 32) {
        #pragma unroll
        for (int r = 0; r < 4; ++r) {            // A: 128 rows x 32 k
            int e = r * 256 + tid, row = e >> 3, kq = e & 7;
            if constexpr (VEC) {
                float4 v = *(const float4*)&Ab[(size_t)(m0 + row) * lda + k0 + kq * 4];
                As[(kq * 4 + 0) * LDA_ + row] = v.x;
                As[(kq * 4 + 1) * LDA_ + row] = v.y;
                As[(kq * 4 + 2) * LDA_ + row] = v.z;
                As[(kq * 4 + 3) * LDA_ + row] = v.w;
            } else {
                #pragma unroll
                for (int j = 0; j < 4; ++j) {
                    int kg = k0 + kq * 4 + j;
                    As[(kq * 4 + j) * LDA_ + row] =
                        (kg < Kd) ? Ab[(size_t)(m0 + row) * lda + kg] : 0.f;
                }
            }
        }
        #pragma unroll
        for (int r = 0; r < 2; ++r) {            // B: 64 rows x 32 k
            int e = r * 256 + tid, row = e >> 3, kq = e & 7;
            if constexpr (VEC) {
                float4 v = *(const float4*)&Bb[(size_t)(n0 + row) * ldbe + k0 + kq * 4];
                Bs[(kq * 4 + 0) * LDB_ + row] = v.x;
                Bs[(kq * 4 + 1) * LDB_ + row] = v.y;
                Bs[(kq * 4 + 2) * LDB_ + row] = v.z;
                Bs[(kq * 4 + 3) * LDB_ + row] = v.w;
            } else {
                #pragma unroll
                for (int j = 0; j < 4; ++j) {
                    int kg = k0 + kq * 4 + j;
                    Bs[(kq * 4 + j) * LDB_ + row] =
                        (kg < Kd) ? Bb[(size_t)(n0 + row) * ldbe + kg] : 0.f;
                }
            }
        }
        __syncthreads();

        int klen = Kd - k0; if (klen > 32) klen = 32;
        if (klen == 32) {
            #pragma unroll 8
            for (int kk = 0; kk < 32; ++kk) MM_BODY(kk);
        } else {
            for (int kk = 0; kk < klen; ++kk) MM_BODY(kk);
        }
        __syncthreads();
    }

    if constexpr (MODE == MODE_DIST) {
        const int b = b0 + blockIdx.z;
        const float* xxb = xx + b * N_PTS;
        float4 xjv = *(const float4*)&xxb[n0 + tx * 4];
        float xj[4] = {xjv.x, xjv.y, xjv.z, xjv.w};
        const int dmn = n0 - m0;
        const bool dblk = (dmn > -64) && (dmn < 128);   // j-tile may hit diagonal
        #pragma unroll
        for (int ih = 0; ih < 2; ++ih)
            #pragma unroll
            for (int i = 0; i < 4; ++i) {
                int gi = m0 + ih * 64 + ty * 4 + i;
                float xi = xxb[gi];
                size_t base = ((size_t)blockIdx.z * N_PTS + gi) * N_PTS;
                int gj = n0 + tx * 4;
                float4 v;
                v.x = 2.f * acc[ih][i][0] - xi - xj[0];
                v.y = 2.f * acc[ih][i][1] - xi - xj[1];
                v.z = 2.f * acc[ih][i][2] - xi - xj[2];
                v.w = 2.f * acc[ih][i][3] - xi - xj[3];
                if (dblk) {
                    if (gi == gj + 0) v.x = 0.f;
                    if (gi == gj + 1) v.y = 0.f;
                    if (gi == gj + 2) v.z = 0.f;
                    if (gi == gj + 3) v.w = 0.f;
                }
                *(float4*)&C1[base + gj] = v;
            }
    } else {  // MODE_GD
        const int Oo = Nn >> 1;
        #pragma unroll
        for (int ih = 0; ih < 2; ++ih)
            #pragma unroll
            for (int i = 0; i < 4; ++i) {
                int row = m0 + ih * 64 + ty * 4 + i;
                int colg = n0 + tx * 4;
                float4 v = make_float4(acc[ih][i][0], acc[ih][i][1],
                                       acc[ih][i][2], acc[ih][i][3]);
                if (colg < Oo) *(float4*)&C1[(size_t)row * Oo + colg] = v;
                else           *(float4*)&C2[(size_t)row * Oo + colg - Oo] = v;
            }
    }
}

// ---------------------------------------------------------------- bf16 MFMA GEMM (layer 5)
__launch_bounds__(256)
__global__ void k_gemm5(const unsigned short* __restrict__ Ah,
                        const unsigned short* __restrict__ Bh,
                        float* __restrict__ Cf)
{
    constexpr int LDA = 72;
    __shared__ unsigned short As[128 * LDA];
    __shared__ unsigned short Bs[128 * LDA];
    const int tid  = threadIdx.x;
    const int lane = tid & 63;
    const int w    = tid >> 6;
    const int wr   = w >> 1, wcl = w & 1;
    const int quad = lane >> 4;
    const int l16  = lane & 15;
    const int m0 = blockIdx.y * 128;
    const int n0 = blockIdx.x * 128;

    f32x4 acc[4][4] = {};

    for (int k0 = 0; k0 < 512; k0 += 64) {
        #pragma unroll
        for (int r = 0; r < 4; ++r) {
            int e = r * 256 + tid, row = e >> 3, kq = e & 7;
            *(uint4*)&As[row * LDA + kq * 8] =
                *(const uint4*)&Ah[(size_t)(m0 + row) * 512 + k0 + kq * 8];
        }
        #pragma unroll
        for (int r = 0; r < 4; ++r) {
            int e = r * 256 + tid, row = e >> 3, kq = e & 7;
            *(uint4*)&Bs[row * LDA + kq * 8] =
                *(const uint4*)&Bh[(size_t)(n0 + row) * 512 + k0 + kq * 8];
        }
        __syncthreads();
        #pragma unroll
        for (int kk = 0; kk < 64; kk += 32) {
            bf16x8 af[4], bfr[4];
            #pragma unroll
            for (int i = 0; i < 4; ++i)
                af[i] = *(const bf16x8*)&As[(wr * 64 + i * 16 + l16) * LDA + kk + quad * 8];
            #pragma unroll
            for (int j = 0; j < 4; ++j)
                bfr[j] = *(const bf16x8*)&Bs[(wcl * 64 + j * 16 + l16) * LDA + kk + quad * 8];
            #pragma unroll
            for (int i = 0; i < 4; ++i)
                #pragma unroll
                for (int j = 0; j < 4; ++j)
                    acc[i][j] = __builtin_amdgcn_mfma_f32_16x16x32_bf16(af[i], bfr[j], acc[i][j], 0, 0, 0);
        }
        __syncthreads();
    }

    #pragma unroll
    for (int i = 0; i < 4; ++i) {
        int rbase = m0 + wr * 64 + i * 16 + quad * 4;
        #pragma unroll
        for (int j = 0; j < 4; ++j) {
            int col = n0 + wcl * 64 + j * 16 + l16;
            #pragma unroll
            for (int r = 0; r < 4; ++r)
                Cf[(size_t)(rbase + r) * 1024 + col] = acc[i][j][r];
        }
    }
}

// ---------------------------------------------------------------- top-20 select
__launch_bounds__(256)
__global__ void k_select(const float* __restrict__ D2, int b0, int* __restrict__ idx_out)
{
    const int lane = threadIdx.x & 63;
    const int w    = threadIdx.x >> 6;
    const int qloc = blockIdx.x * 4 + w;
    const int bl   = qloc >> 11;
    const int n    = qloc & 2047;
    const float* row = D2 + (size_t)qloc * N_PTS;

    unsigned key[32];
    #pragma unroll
    for (int c = 0; c < 8; ++c) {
        float4 v = *(const float4*)&row[c * 256 + lane * 4];
        float vv[4] = {v.x, v.y, v.z, v.w};
        #pragma unroll
        for (int r = 0; r < 4; ++r) {
            unsigned u = __float_as_uint(vv[r]);
            key[c * 4 + r] = ((int)u >= 0) ? (u | 0x80000000u) : ~u;
        }
    }

    unsigned lo = 0u, hi = 0xFFFFFFFFu;
    while (lo < hi) {
        unsigned mid = lo + ((hi - lo) >> 1);
        int cnt = 0;
        #pragma unroll
        for (int e = 0; e < 32; ++e) cnt += (key[e] > mid) ? 1 : 0;
        #pragma unroll
        for (int s = 32; s >= 1; s >>= 1) cnt += __shfl_xor(cnt, s, 64);
        cnt = __builtin_amdgcn_readfirstlane(cnt);
        if (cnt < KNN) hi = mid; else lo = mid + 1;
    }
    const unsigned T = lo;

    int* outp = idx_out + (size_t)((b0 + bl) * N_PTS + n) * KNN;
    const unsigned long long ltmask = (lane == 0) ? 0ull : (~0ull >> (64 - lane));
    int base = 0;
    #pragma unroll
    for (int e = 0; e < 32; ++e) {
        bool p = key[e] > T;
        unsigned long long m = __ballot(p);
        if (p) {
            int pos = base + __popcll(m & ltmask);
            outp[pos] = (e >> 2) * 256 + lane * 4 + (e & 3);
        }
        base += __popcll(m);
    }
    for (int e = 0; e < 32 && base < KNN; ++e) {
        bool p = key[e] == T;
        unsigned long long m = __ballot(p);
        if (p) {
            int pos = base + __popcll(m & ltmask);
            if (pos < KNN) outp[pos] = (e >> 2) * 256 + lane * 4 + (e & 3);
        }
        base += __popcll(m);
    }
}

// ---------------------------------------------------------------- gather + stats
// XCD-locality swizzle: batch = blockIdx&3, so each batch's gtab slice
// (<= 2 MB) stays resident in the 4 MB L2 of the XCD(s) serving it.
template<int O, int NSEQ>
__launch_bounds__(256)
__global__ void k_gather(const float* __restrict__ gtab, const float* __restrict__ dtab,
                         const int* __restrict__ idx,
                         float* __restrict__ hmax, float* __restrict__ hmin,
                         float* __restrict__ ssum, float* __restrict__ ssumsq)
{
    constexpr int NPB = 256 / O;
    const int grp = threadIdx.x / O;
    const int o   = threadIdx.x & (O - 1);
    float accS = 0.f, accS2 = 0.f;
    const int rowsPerBlock = NPB * NSEQ;
    const int batch = blockIdx.x & 3;
    const int chunk = blockIdx.x >> 2;
    const int bbase = batch << 11;
    for (int s = 0; s < NSEQ; ++s) {
        int row = bbase + chunk * rowsPerBlock + s * NPB + grp;
        const int* ip = idx + (size_t)row * KNN;
        float gmax = -INFINITY, gmin = INFINITY, gs = 0.f, gs2 = 0.f;
        for (int k = 0; k < KNN; ++k) {
            int nb = ip[k];
            float v = gtab[(size_t)(bbase + nb) * O + o];
            gmax = fmaxf(gmax, v);
            gmin = fminf(gmin, v);
            gs  += v;
            gs2  = fmaf(v, v, gs2);
        }
        float d = dtab[(size_t)row * O + o];
        hmax[(size_t)row * O + o] = gmax + d;
        hmin[(size_t)row * O + o] = gmin + d;
        accS  += gs + (float)KNN * d;
        accS2 += gs2 + 2.f * d * gs + (float)KNN * d * d;
    }
    int bank = blockIdx.x & 63;
    atomicAdd(&ssum[bank * O + o], accS);
    atomicAdd(&ssumsq[bank * O + o], accS2);
}

// ---------------------------------------------------------------- normalize (+BN finalize, +xx, +bf16 mirror)
template<int O, bool WRITE_XX>
__launch_bounds__(256)
__global__ void k_normalize(const float* __restrict__ hmax, const float* __restrict__ hmin,
                            const float* __restrict__ ssum, const float* __restrict__ ssumsq,
                            const float* __restrict__ gamma, const float* __restrict__ beta,
                            float invM, float* __restrict__ xcs,
                            __hip_bfloat16* __restrict__ xch, float* __restrict__ xx)
{
    const int tid = threadIdx.x;
    const int o   = tid & (O - 1);
    float s = 0.f, s2 = 0.f;
    #pragma unroll 8
    for (int bk = 0; bk < 64; ++bk) { s += ssum[bk * O + o]; s2 += ssumsq[bk * O + o]; }
    float mean = s * invM;
    float var  = fmaf(-mean, mean, s2 * invM);
    float sc   = gamma[o] * rsqrtf(var + EPSV);
    float sh   = beta[o] - mean * sc;

    constexpr int R = 256 / O;
    const int rloc = tid / O;
    __shared__ float part[4];
    const int ngroups = BN_ROWS / R;
    for (int gidx = blockIdx.x; gidx < ngroups; gidx += gridDim.x) {
        int row = gidx * R + rloc;
        size_t i = (size_t)row * O + o;
        float h = (sc >= 0.f) ? hmax[i] : hmin[i];
        float y = fmaf(h, sc, sh);
        y = (y >= 0.f) ? y : SLOPEV * y;
        xcs[(size_t)row * 512 + o] = y;
        xch[(size_t)row * 512 + o] = __float2bfloat16(y);
        if constexpr (WRITE_XX) {
            float p = y * y;
            #pragma unroll
            for (int sft = 32; sft >= 1; sft >>= 1) p += __shfl_xor(p, sft, 64);
            if constexpr (O == 64) {
                if ((tid & 63) == 0) xx[row] = p;
            } else {
                if ((tid & 63) == 0) part[tid >> 6] = p;
                __syncthreads();
                if constexpr (O == 128) {
                    if (tid < 2) xx[gidx * R + tid] = part[2 * tid] + part[2 * tid + 1];
                } else {
                    if (tid == 0) xx[gidx * R] = (part[0] + part[1]) + (part[2] + part[3]);
                }
                __syncthreads();
            }
        }
    }
}

// ---------------------------------------------------------------- layer-5 stats (16 banks)
__global__ void k_stats5(const float* __restrict__ h, float* __restrict__ ssum, float* __restrict__ ssumsq)
{
    int o  = blockIdx.y * 256 + threadIdx.x;
    int r0 = blockIdx.x * 512;
    float s = 0.f, s2 = 0.f;
    for (int r = 0; r < 512; ++r) {
        float v = h[(size_t)(r0 + r) * 1024 + o];
        s += v; s2 = fmaf(v, v, s2);
    }
    ssum[blockIdx.x * 1024 + o]   = s;
    ssumsq[blockIdx.x * 1024 + o] = s2;
}

// ---------------------------------------------------------------- seg max/sum (+finalize)
__global__ void k_seg(const float* __restrict__ h,
                      const float* __restrict__ ssum, const float* __restrict__ ssumsq,
                      const float* __restrict__ gamma, const float* __restrict__ beta,
                      float* __restrict__ smax, float* __restrict__ ssumseg)
{
    int f = blockIdx.y * 256 + threadIdx.x;
    float s = 0.f, s2 = 0.f;
    #pragma unroll
    for (int bk = 0; bk < 16; ++bk) { s += ssum[bk * 1024 + f]; s2 += ssumsq[bk * 1024 + f]; }
    const float invM = 1.f / (float)BN_ROWS;
    float mean = s * invM;
    float var  = fmaf(-mean, mean, s2 * invM);
    float sc   = gamma[f] * rsqrtf(var + EPSV);
    float sh   = beta[f] - mean * sc;

    int seg = blockIdx.x;
    float mx = -INFINITY, sm = 0.f;
    int n0 = seg * 64;
    for (int i = 0; i < 64; ++i) {
        float v = fmaf(h[(size_t)(n0 + i) * 1024 + f], sc, sh);
        v = (v >= 0.f) ? v : SLOPEV * v;
        mx = fmaxf(mx, v); sm += v;
    }
    smax[(size_t)seg * 1024 + f]    = mx;
    ssumseg[(size_t)seg * 1024 + f] = sm;
}

// ---------------------------------------------------------------- final projection (+bin combine)
__launch_bounds__(256)
__global__ void k_final(const float* __restrict__ smax, const float* __restrict__ ssg,
                        const float* __restrict__ Wf, const float* __restrict__ bfeat,
                        float* __restrict__ out)
{
    __shared__ float row[1024];
    int sb = blockIdx.x;             // s*4 + b, s in 0..62
    int s = sb >> 2, b = sb & 3;
    int nb = (s == 0) ? 1 : (s < 3) ? 2 : (s < 7) ? 4 : (s < 15) ? 8 : (s < 31) ? 16 : 32;
    int idxL = s - (nb - 1);
    int segc = 32 / nb;
    int seg0 = b * 32 + idxL * segc;
    float inv = 1.f / (float)(64 * segc);
    for (int c = threadIdx.x; c < 1024; c += 256) {
        float mx = -INFINITY, sm = 0.f;
        for (int t = 0; t < segc; ++t) {
            mx = fmaxf(mx, smax[(size_t)(seg0 + t) * 1024 + c]);
            sm += ssg[(size_t)(seg0 + t) * 1024 + c];
        }
        row[c] = mx + sm * inv;
    }
    __syncthreads();
    int o = threadIdx.x;
    const float* w = Wf + (size_t)o * 1024;
    float acc = 0.f;
    for (int fb = 0; fb < 1024; fb += 4) {
        float4 w4 = *(const float4*)&w[fb];
        acc = fmaf(row[fb + 0], w4.x, acc);
        acc = fmaf(row[fb + 1], w4.y, acc);
        acc = fmaf(row[fb + 2], w4.z, acc);
        acc = fmaf(row[fb + 3], w4.w, acc);
    }
    out[(size_t)sb * 256 + o] = acc + bfeat[o];
}

// ================================================================ launch
extern "C" void kernel_launch(void* const* d_in, const int* in_sizes, int n_in,
                              void* d_out, int out_size, void* d_ws, size_t ws_size,
                              hipStream_t stream)
{
    const float* x  = (const float*)d_in[0];
    const float* W1 = (const float*)d_in[1];
    const float* g1 = (const float*)d_in[2];
    const float* b1 = (const float*)d_in[3];
    const float* W2 = (const float*)d_in[4];
    const float* g2 = (const float*)d_in[5];
    const float* b2 = (const float*)d_in[6];
    const float* W3 = (const float*)d_in[7];
    const float* g3 = (const float*)d_in[8];
    const float* b3 = (const float*)d_in[9];
    const float* W4 = (const float*)d_in[10];
    const float* g4 = (const float*)d_in[11];
    const float* b4 = (const float*)d_in[12];
    const float* W5 = (const float*)d_in[13];
    const float* g5 = (const float*)d_in[14];
    const float* b5 = (const float*)d_in[15];
    const float* Wf = (const float*)d_in[16];
    const float* bfeat = (const float*)d_in[17];
    float* out = (float*)d_out;
    float* ws  = (float*)d_ws;

    // workspace layout (floats), total 19,784,192 = 79.1 MB (unchanged)
    float* xt1   = ws + 0;            // 24576
    int*   idx   = (int*)(ws + 24576);// 163840
    float* xx    = ws + 188416;       // 8192
    float* xc    = ws + 196608;       // 8192*512
    float* hmax  = ws + 4390912;      // 8192*256
    float* hmin  = ws + 6488064;      // 8192*256
    float* stats = ws + 8585216;      // 98304 (L1@0 L2@8192 L3@16384 L4@32768 L5@65536)
    float* smax  = ws + 8683520;      // 128*1024
    float* ssg   = ws + 8814592;      // 128*1024
    float* wc    = ws + 8945664;      // 90624 (L1@0 L2@384 L3@8576 L4@24960)
    float* big   = ws + 9036288;      // 8,388,608 (D2 | gtab+dtab | h5)
    float* gtab  = big;               // up to 8192*256
    float* dtab  = big + 2097152;     // up to 8192*256
    __hip_bfloat16* xch = (__hip_bfloat16*)(ws + 17424896);  // 8192*512 bf16
    __hip_bfloat16* w5h = (__hip_bfloat16*)(ws + 19522048);  // 1024*512 bf16

    hipMemsetAsync(stats, 0, 98304 * sizeof(float), stream);
    k_transpose<<<32, 256, 0, stream>>>(x, xt1, xx);
    k_prepw_all<<<2402, 256, 0, stream>>>(W1, W2, W3, W4, W5, wc, w5h);

    const float invMk = 1.f / (float)(BN_ROWS * KNN);

    // ------------- layer 1: C=3, O=64
    {
        float* ss = stats + 0;
        for (int c = 0; c < 2; ++c) {
            k_mm128<MODE_DIST, false><<<dim3(32, 16, 2), 256, 0, stream>>>(xt1, 3, nullptr, 0, xx, 2*c, big, nullptr, N_PTS, 3);
            k_select<<<1024, 256, 0, stream>>>(big, 2*c, idx);
        }
        k_mm128<MODE_GD, false><<<dim3(2, 64, 1), 256, 0, stream>>>(xt1, 3, wc, 3, nullptr, 0, gtab, dtab, 128, 3);
        k_gather<64, 8><<<256, 256, 0, stream>>>(gtab, dtab, idx, hmax, hmin, ss, ss + 4096);
        k_normalize<64, true><<<512, 256, 0, stream>>>(hmax, hmin, ss, ss + 4096, g1, b1, invMk, xc + 0, xch + 0, xx);
    }
    // ------------- layer 2: C=64, O=64
    {
        float* ss = stats + 8192;
        for (int c = 0; c < 2; ++c) {
            k_mm128<MODE_DIST, true><<<dim3(32, 16, 2), 256, 0, stream>>>(xc + 0, 512, nullptr, 0, xx, 2*c, big, nullptr, N_PTS, 64);
            k_select<<<1024, 256, 0, stream>>>(big, 2*c, idx);
        }
        k_mm128<MODE_GD, true><<<dim3(2, 64, 1), 256, 0, stream>>>(xc + 0, 512, wc + 384, 64, nullptr, 0, gtab, dtab, 128, 64);
        k_gather<64, 8><<<256, 256, 0, stream>>>(gtab, dtab, idx, hmax, hmin, ss, ss + 4096);
        k_normalize<64, true><<<512, 256, 0, stream>>>(hmax, hmin, ss, ss + 4096, g2, b2, invMk, xc + 64, xch + 64, xx);
    }
    // ------------- layer 3: C=64, O=128
    {
        float* ss = stats + 16384;
        for (int c = 0; c < 2; ++c) {
            k_mm128<MODE_DIST, true><<<dim3(32, 16, 2), 256, 0, stream>>>(xc + 64, 512, nullptr, 0, xx, 2*c, big, nullptr, N_PTS, 64);
            k_select<<<1024, 256, 0, stream>>>(big, 2*c, idx);
        }
        k_mm128<MODE_GD, true><<<dim3(4, 64, 1), 256, 0, stream>>>(xc + 64, 512, wc + 8576, 64, nullptr, 0, gtab, dtab, 256, 64);
        k_gather<128, 8><<<512, 256, 0, stream>>>(gtab, dtab, idx, hmax, hmin, ss, ss + 8192);
        k_normalize<128, true><<<512, 256, 0, stream>>>(hmax, hmin, ss, ss + 8192, g3, b3, invMk, xc + 128, xch + 128, xx);
    }
    // ------------- layer 4: C=128, O=256
    {
        float* ss = stats + 32768;
        for (int c = 0; c < 2; ++c) {
            k_mm128<MODE_DIST, true><<<dim3(32, 16, 2), 256, 0, stream>>>(xc + 128, 512, nullptr, 0, xx, 2*c, big, nullptr, N_PTS, 128);
            k_select<<<1024, 256, 0, stream>>>(big, 2*c, idx);
        }
        k_mm128<MODE_GD, true><<<dim3(8, 64, 1), 256, 0, stream>>>(xc + 128, 512, wc + 24960, 128, nullptr, 0, gtab, dtab, 512, 128);
        k_gather<256, 8><<<1024, 256, 0, stream>>>(gtab, dtab, idx, hmax, hmin, ss, ss + 16384);
        k_normalize<256, false><<<512, 256, 0, stream>>>(hmax, hmin, ss, ss + 16384, g4, b4, invMk, xc + 256, xch + 256, xx);
    }
    // ------------- layer 5: bf16 MFMA GEMM, then stats/seg/final
    {
        float* ss = stats + 65536;
        k_gemm5<<<dim3(8, 64), 256, 0, stream>>>((const unsigned short*)xch, (const unsigned short*)w5h, big);
        k_stats5<<<dim3(16, 4), 256, 0, stream>>>(big, ss, ss + 16384);
        k_seg<<<dim3(128, 4), 256, 0, stream>>>(big, ss, ss + 16384, g5, b5, smax, ssg);
        k_final<<<252, 256, 0, stream>>>(smax, ssg, Wf, bfeat, out);
    }
}